// Round 15
// baseline (276.136 us; speedup 1.0000x reference)
//
#include <hip/hip_runtime.h>

#define NN 50000
#define NE 1600000
#define D  32
#define NRANGE 256
#define RC  8192      // entries per range region; E[6250], +24 sigma
#define EPB 16384     // edges per pass-1 block
#define SPLIT 2       // gather concurrency split

typedef short bf16x8 __attribute__((ext_vector_type(8)));
typedef float f32x4  __attribute__((ext_vector_type(4)));

__device__ __forceinline__ float b2f(unsigned short v) {
    return __uint_as_float(((unsigned)v) << 16);
}
__device__ __forceinline__ unsigned short f2b(float f) {   // round-to-nearest-even
    unsigned u = __float_as_uint(f);
    u += 0x7FFFu + ((u >> 16) & 1u);
    return (unsigned short)(u >> 16);
}
__device__ __forceinline__ uint2 pkbf4(float4 v) {         // 4 f32 -> 4 bf16 (8B)
    uint2 r;
    r.x = (unsigned)f2b(v.x) | ((unsigned)f2b(v.y) << 16);
    r.y = (unsigned)f2b(v.z) | ((unsigned)f2b(v.w) << 16);
    return r;
}

__device__ __forceinline__ int range_of(int s)  { return (int)(((unsigned)s * 256u) / 50000u); }
__device__ __forceinline__ int range_beg(int r) { return (int)(((unsigned)r * 50000u + 255u) >> 8); }

// ---------------------------------------------------------------------------
// Pass 1: partition edges into 256 node-range regions, COALESCED writes.
// ---------------------------------------------------------------------------
__global__ __launch_bounds__(1024) void k_part1(const int* __restrict__ src,
                                                int* __restrict__ cursor,
                                                unsigned int* __restrict__ buf) {
    __shared__ unsigned int sbuf[EPB];       // 64 KB
    __shared__ int hist[NRANGE];
    __shared__ int scanb[NRANGE];
    __shared__ int lofs[NRANGE + 1];
    __shared__ int gbase[NRANGE];

    const int t = threadIdx.x;
    const long long e0 = (long long)blockIdx.x * EPB;

    for (int r = t; r < NRANGE; r += 1024) hist[r] = 0;
    __syncthreads();

    int myr[16], myrank[16], mys[16];
#pragma unroll
    for (int k = 0; k < 16; k++) {
        long long e = e0 + t + (long long)k * 1024;
        int r = -1, rk = 0, s = 0;
        if (e < NE) {
            s = src[e];
            r = range_of(s);
            rk = atomicAdd(&hist[r], 1);
        }
        myr[k] = r; myrank[k] = rk; mys[k] = s;
    }
    __syncthreads();

    if (t < NRANGE) {
        gbase[t] = atomicAdd(&cursor[t], hist[t]);
        scanb[t] = hist[t];
    }
    __syncthreads();
    for (int off = 1; off < NRANGE; off <<= 1) {       // Hillis-Steele inclusive
        int v = 0;
        if (t < NRANGE && t >= off) v = scanb[t - off];
        __syncthreads();
        if (t < NRANGE) scanb[t] += v;
        __syncthreads();
    }
    if (t < NRANGE) lofs[t + 1] = scanb[t];
    if (t == 0) lofs[0] = 0;
    __syncthreads();

#pragma unroll
    for (int k = 0; k < 16; k++) {
        if (myr[k] >= 0) {
            int r = myr[k];
            unsigned int pk = (unsigned int)(e0 + t + (long long)k * 1024)
                            | ((unsigned int)(mys[k] - range_beg(r)) << 21);
            sbuf[lofs[r] + myrank[k]] = pk;
        }
    }
    __syncthreads();

    const int total = lofs[NRANGE];
    for (int i = t; i < total; i += 1024) {
        int lo = 0, hi = NRANGE - 1;                   // find r: lofs[r]<=i<lofs[r+1]
        while (lo < hi) { int mid = (lo + hi + 1) >> 1; if (lofs[mid] <= i) lo = mid; else hi = mid - 1; }
        buf[(size_t)lo * RC + gbase[lo] + (i - lofs[lo])] = sbuf[i];
    }
}

// ---------------------------------------------------------------------------
// Pass 2: one block per range; LDS-sort entries by local node id -> exact CSR.
// ---------------------------------------------------------------------------
__global__ __launch_bounds__(1024) void k_part2(const int* __restrict__ cursor,
                                                const unsigned int* __restrict__ buf,
                                                int* __restrict__ eid,
                                                int* __restrict__ node_off,
                                                int* __restrict__ node_cnt) {
    __shared__ int sout[RC];                 // 32 KB
    __shared__ int hist[NRANGE];
    __shared__ int scanb[NRANGE];
    __shared__ int lofs[NRANGE + 1];

    const int r = blockIdx.x;
    const int t = threadIdx.x;
    int cnt = cursor[r];
    if (cnt > RC) cnt = RC;                  // impossible; guards OOB
    const int sbeg = range_beg(r);
    const int nr = range_beg(r + 1) - sbeg;  // nodes in this range (<=196)

    for (int i = t; i < NRANGE; i += 1024) hist[i] = 0;
    __syncthreads();

    unsigned int mypk[8]; int myrk[8];
#pragma unroll
    for (int k = 0; k < 8; k++) {
        int i = t + k * 1024;
        unsigned int pk = 0; int rk = 0;
        if (i < cnt) {
            pk = buf[(size_t)r * RC + i];
            rk = atomicAdd(&hist[pk >> 21], 1);
        }
        mypk[k] = pk; myrk[k] = rk;
    }
    __syncthreads();

    if (t < NRANGE) scanb[t] = hist[t];
    __syncthreads();
    for (int off = 1; off < NRANGE; off <<= 1) {
        int v = 0;
        if (t < NRANGE && t >= off) v = scanb[t - off];
        __syncthreads();
        if (t < NRANGE) scanb[t] += v;
        __syncthreads();
    }
    if (t < NRANGE) lofs[t + 1] = scanb[t];
    if (t == 0) lofs[0] = 0;
    __syncthreads();

#pragma unroll
    for (int k = 0; k < 8; k++) {
        int i = t + k * 1024;
        if (i < cnt) {
            unsigned int pk = mypk[k];
            sout[lofs[pk >> 21] + myrk[k]] = (int)(pk & 0x1FFFFFu);
        }
    }
    __syncthreads();

    for (int i = t; i < cnt; i += 1024) eid[(size_t)r * RC + i] = sout[i];
    if (t < nr) {
        node_off[sbeg + t] = r * RC + lofs[t];
        node_cnt[sbeg + t] = hist[t];
    }
}

// ---------------------------------------------------------------------------
// Segment-sum gather over the exact CSR + piggyback f32->bf16 conversion of
// each ew row (each edge is in exactly one src bucket -> converted exactly
// once; full 64B-line stores, no RMW).  Conversion uses the same f2b rounding
// k_edge applied in R14 -> bitwise-identical output.
// ---------------------------------------------------------------------------
__global__ __launch_bounds__(256) void k_gather(const float* __restrict__ ew,
                                                const int* __restrict__ node_off,
                                                const int* __restrict__ node_cnt,
                                                const int* __restrict__ eid,
                                                float* __restrict__ parts,
                                                unsigned short* __restrict__ ewb) {
    int i = blockIdx.x * 256 + threadIdx.x;     // over NN*SPLIT*8 = 800K (exact grid)
    int q = i & 7;
    int t2 = i >> 3;
    int c = t2 & 1;
    int n = t2 >> 1;
    const int qo = q << 2;

    const int beg = node_off[n];
    const int cnt = node_cnt[n];
    const int half = (cnt + 1) >> 1;
    int r0 = c * half;
    int r1 = r0 + half; if (r1 > cnt) r1 = cnt;
    const int* bucket = eid + beg;

    float4 acc = make_float4(0.f, 0.f, 0.f, 0.f);
    int r = r0;
    for (; r + 4 <= r1; r += 4) {
        int ea = bucket[r + 0];
        int eb = bucket[r + 1];
        int ec = bucket[r + 2];
        int ed = bucket[r + 3];
        float4 v0 = *reinterpret_cast<const float4*>(ew + (size_t)ea * D + qo);
        float4 v1 = *reinterpret_cast<const float4*>(ew + (size_t)eb * D + qo);
        float4 v2 = *reinterpret_cast<const float4*>(ew + (size_t)ec * D + qo);
        float4 v3 = *reinterpret_cast<const float4*>(ew + (size_t)ed * D + qo);
        acc.x += (v0.x + v1.x) + (v2.x + v3.x);
        acc.y += (v0.y + v1.y) + (v2.y + v3.y);
        acc.z += (v0.z + v1.z) + (v2.z + v3.z);
        acc.w += (v0.w + v1.w) + (v2.w + v3.w);
        if (ewb) {
            *reinterpret_cast<uint2*>(ewb + (size_t)ea * D + qo) = pkbf4(v0);
            *reinterpret_cast<uint2*>(ewb + (size_t)eb * D + qo) = pkbf4(v1);
            *reinterpret_cast<uint2*>(ewb + (size_t)ec * D + qo) = pkbf4(v2);
            *reinterpret_cast<uint2*>(ewb + (size_t)ed * D + qo) = pkbf4(v3);
        }
    }
    for (; r < r1; ++r) {
        int e0 = bucket[r];
        float4 v0 = *reinterpret_cast<const float4*>(ew + (size_t)e0 * D + qo);
        acc.x += v0.x; acc.y += v0.y; acc.z += v0.z; acc.w += v0.w;
        if (ewb)
            *reinterpret_cast<uint2*>(ewb + (size_t)e0 * D + qo) = pkbf4(v0);
    }
    *reinterpret_cast<float4*>(parts + ((size_t)c * NN + n) * D + qo) = acc;
}

// ---------------------------------------------------------------------------
// node_term (bf16) = x@w_x + (p0+p1)@w_ew_j   (unchanged)
// ---------------------------------------------------------------------------
__global__ __launch_bounds__(256) void k_node(const float* __restrict__ x,
                                              const float* __restrict__ parts,
                                              const float* __restrict__ w_x,
                                              const float* __restrict__ w_ew_j,
                                              unsigned short* __restrict__ node_term) {
    int i = blockIdx.x * 256 + threadIdx.x;     // n*32 + o (exact grid)
    int n = i >> 5, o = i & 31;
    const float* p0 = parts + (size_t)n * D;
    const float* p1 = parts + ((size_t)NN + n) * D;
    float acc = 0.f;
#pragma unroll
    for (int k = 0; k < D; k++) {
        float sw = p0[k] + p1[k];
        acc += x[(size_t)n * D + k] * w_x[k * D + o] + sw * w_ew_j[k * D + o];
    }
    node_term[i] = f2b(acc);
}

// ---------------------------------------------------------------------------
// MFMA k_edge (R14 structure).  A-fragment comes from pre-converted bf16 ewb
// (one 16B load, zero VALU convert) when available; FETCH 200->~112MB.
// Fallback: f32 ew + in-kernel conversion (bitwise-identical result).
// ---------------------------------------------------------------------------
__global__ __launch_bounds__(256) void k_edge_mfma(const float* __restrict__ ew,
                                                   const unsigned short* __restrict__ ewb,
                                                   const int* __restrict__ src,
                                                   const int* __restrict__ dst,
                                                   const unsigned short* __restrict__ nt,
                                                   const float* __restrict__ w_ew_i,
                                                   float* __restrict__ out) {
    const int lane = threadIdx.x & 63;
    const int wid  = (blockIdx.x * 256 + threadIdx.x) >> 6;
    const int ma   = lane & 15;       // A row / C col
    const int kb   = lane >> 4;       // k-block (8 k each) / C row-block

    // B fragments (loaded once): b[nh][j] = w_ew_i[8*kb+j][nh*16+ma]
    bf16x8 bfrag[2];
#pragma unroll
    for (int nh = 0; nh < 2; nh++) {
#pragma unroll
        for (int j = 0; j < 8; j++)
            bfrag[nh][j] = (short)f2b(w_ew_i[(8 * kb + j) * D + nh * 16 + ma]);
    }

    const int ebase = wid * 64;
#pragma unroll
    for (int t = 0; t < 4; t++) {
        const int e0 = ebase + t * 16;

        // A fragment: a[j] = ew[e0+ma][8*kb+j]
        bf16x8 afrag;
        if (ewb) {
            afrag = *reinterpret_cast<const bf16x8*>(ewb + (size_t)(e0 + ma) * D + 8 * kb);
        } else {
            const float4* ap = reinterpret_cast<const float4*>(ew + (size_t)(e0 + ma) * D + 8 * kb);
            float4 alo = ap[0];
            float4 ahi = ap[1];
            afrag[0] = (short)f2b(alo.x); afrag[1] = (short)f2b(alo.y);
            afrag[2] = (short)f2b(alo.z); afrag[3] = (short)f2b(alo.w);
            afrag[4] = (short)f2b(ahi.x); afrag[5] = (short)f2b(ahi.y);
            afrag[6] = (short)f2b(ahi.z); afrag[7] = (short)f2b(ahi.w);
        }

        // C rows owned by this lane: edges e0 + kb*4 + r, r=0..3
        int4 s4 = *reinterpret_cast<const int4*>(src + e0 + kb * 4);
        int4 d4 = *reinterpret_cast<const int4*>(dst + e0 + kb * 4);
        const int se[4] = {s4.x, s4.y, s4.z, s4.w};
        const int de[4] = {d4.x, d4.y, d4.z, d4.w};

#pragma unroll
        for (int nh = 0; nh < 2; nh++) {
            const int col = nh * 16 + ma;
            f32x4 c;
#pragma unroll
            for (int r = 0; r < 4; r++)
                c[r] = b2f(nt[(size_t)se[r] * D + col]) + b2f(nt[(size_t)de[r] * D + col]);

            c = __builtin_amdgcn_mfma_f32_16x16x32_bf16(afrag, bfrag[nh], c, 0, 0, 0);

#pragma unroll
            for (int r = 0; r < 4; r++)
                out[(size_t)(e0 + kb * 4 + r) * D + col] = c[r];
        }
    }
}

// ---------------------------------------------------------------------------
extern "C" void kernel_launch(void* const* d_in, const int* in_sizes, int n_in,
                              void* d_out, int out_size, void* d_ws, size_t ws_size,
                              hipStream_t stream) {
    const float* x      = (const float*)d_in[0];
    const int*   ei     = (const int*)d_in[1];
    const float* ew     = (const float*)d_in[2];
    const float* w_x    = (const float*)d_in[3];
    const float* w_ew_i = (const float*)d_in[4];
    const float* w_ew_j = (const float*)d_in[5];
    float*       out    = (float*)d_out;

    const int* src = ei;            // edge_index[0]
    const int* dst = ei + NE;       // edge_index[1]

    // workspace.  nt (bf16, 3.2MB) overlays buf (dead after part2).
    float*        parts    = (float*)d_ws;                       // [2][NN][D] 12.8 MB
    int*          node_off = (int*)(parts + (size_t)SPLIT * NN * D); // [NN]   200 KB
    int*          node_cnt = node_off + NN;                      // [NN]       200 KB
    int*          cursor   = node_cnt + NN;                      // [NRANGE]     1 KB
    unsigned int* buf      = (unsigned int*)(cursor + NRANGE);   // [NRANGE][RC] 8 MB
    int*          eid      = (int*)(buf + (size_t)NRANGE * RC);  // [NRANGE][RC] 8 MB
    unsigned short* ntb    = (unsigned short*)buf;               // [NN][D] bf16 overlay
    unsigned short* ewb    = (unsigned short*)(eid + (size_t)NRANGE * RC); // [NE][D] bf16 102.4MB

    // bf16 ew cache requires ~132MB of ws; fall back to R14 behavior if short
    const size_t need = ((size_t)(eid + (size_t)NRANGE * RC - (int*)d_ws)) * sizeof(int)
                      + (size_t)NE * D * sizeof(unsigned short);
    if (ws_size < need) ewb = nullptr;

    hipMemsetAsync(cursor, 0, NRANGE * sizeof(int), stream);

    k_part1    <<<(NE + EPB - 1) / EPB,  1024, 0, stream>>>(src, cursor, buf);
    k_part2    <<<NRANGE,                1024, 0, stream>>>(cursor, buf, eid, node_off, node_cnt);
    k_gather   <<<NN * SPLIT * 8 / 256,  256,  0, stream>>>(ew, node_off, node_cnt, eid, parts, ewb);
    k_node     <<<NN * D / 256,          256,  0, stream>>>(x, parts, w_x, w_ew_j, ntb);
    k_edge_mfma<<<NE / 64 / 4,           256,  0, stream>>>(ew, ewb, src, dst, ntb, w_ew_i, out);
}

// Round 16
// 252.910 us; speedup vs baseline: 1.0918x; 1.0918x over previous
//
#include <hip/hip_runtime.h>

#define NN 50000
#define NE 1600000
#define D  32
#define NRANGE 256
#define RC  8192      // entries per range region; E[6250], +24 sigma
#define EPB 16384     // edges per pass-1 block
#define SPLIT 4       // gather concurrency split (R16: 2->4, latency-vs-transaction probe)

__device__ __forceinline__ float b2f(unsigned short v) {
    return __uint_as_float(((unsigned)v) << 16);
}
__device__ __forceinline__ unsigned short f2b(float f) {   // round-to-nearest-even
    unsigned u = __float_as_uint(f);
    u += 0x7FFFu + ((u >> 16) & 1u);
    return (unsigned short)(u >> 16);
}

__device__ __forceinline__ int range_of(int s)  { return (int)(((unsigned)s * 256u) / 50000u); }
__device__ __forceinline__ int range_beg(int r) { return (int)(((unsigned)r * 50000u + 255u) >> 8); }

// ---------------------------------------------------------------------------
// Pass 1: partition edges into 256 node-range regions, COALESCED writes.
// ---------------------------------------------------------------------------
__global__ __launch_bounds__(1024) void k_part1(const int* __restrict__ src,
                                                int* __restrict__ cursor,
                                                unsigned int* __restrict__ buf) {
    __shared__ unsigned int sbuf[EPB];       // 64 KB
    __shared__ int hist[NRANGE];
    __shared__ int scanb[NRANGE];
    __shared__ int lofs[NRANGE + 1];
    __shared__ int gbase[NRANGE];

    const int t = threadIdx.x;
    const long long e0 = (long long)blockIdx.x * EPB;

    for (int r = t; r < NRANGE; r += 1024) hist[r] = 0;
    __syncthreads();

    int myr[16], myrank[16], mys[16];
#pragma unroll
    for (int k = 0; k < 16; k++) {
        long long e = e0 + t + (long long)k * 1024;
        int r = -1, rk = 0, s = 0;
        if (e < NE) {
            s = src[e];
            r = range_of(s);
            rk = atomicAdd(&hist[r], 1);
        }
        myr[k] = r; myrank[k] = rk; mys[k] = s;
    }
    __syncthreads();

    if (t < NRANGE) {
        gbase[t] = atomicAdd(&cursor[t], hist[t]);
        scanb[t] = hist[t];
    }
    __syncthreads();
    for (int off = 1; off < NRANGE; off <<= 1) {       // Hillis-Steele inclusive
        int v = 0;
        if (t < NRANGE && t >= off) v = scanb[t - off];
        __syncthreads();
        if (t < NRANGE) scanb[t] += v;
        __syncthreads();
    }
    if (t < NRANGE) lofs[t + 1] = scanb[t];
    if (t == 0) lofs[0] = 0;
    __syncthreads();

#pragma unroll
    for (int k = 0; k < 16; k++) {
        if (myr[k] >= 0) {
            int r = myr[k];
            unsigned int pk = (unsigned int)(e0 + t + (long long)k * 1024)
                            | ((unsigned int)(mys[k] - range_beg(r)) << 21);
            sbuf[lofs[r] + myrank[k]] = pk;
        }
    }
    __syncthreads();

    const int total = lofs[NRANGE];
    for (int i = t; i < total; i += 1024) {
        int lo = 0, hi = NRANGE - 1;                   // find r: lofs[r]<=i<lofs[r+1]
        while (lo < hi) { int mid = (lo + hi + 1) >> 1; if (lofs[mid] <= i) lo = mid; else hi = mid - 1; }
        buf[(size_t)lo * RC + gbase[lo] + (i - lofs[lo])] = sbuf[i];
    }
}

// ---------------------------------------------------------------------------
// Pass 2: one block per range; LDS-sort entries by local node id -> exact CSR.
// ---------------------------------------------------------------------------
__global__ __launch_bounds__(1024) void k_part2(const int* __restrict__ cursor,
                                                const unsigned int* __restrict__ buf,
                                                int* __restrict__ eid,
                                                int* __restrict__ node_off,
                                                int* __restrict__ node_cnt) {
    __shared__ int sout[RC];                 // 32 KB
    __shared__ int hist[NRANGE];
    __shared__ int scanb[NRANGE];
    __shared__ int lofs[NRANGE + 1];

    const int r = blockIdx.x;
    const int t = threadIdx.x;
    int cnt = cursor[r];
    if (cnt > RC) cnt = RC;                  // impossible; guards OOB
    const int sbeg = range_beg(r);
    const int nr = range_beg(r + 1) - sbeg;  // nodes in this range (<=196)

    for (int i = t; i < NRANGE; i += 1024) hist[i] = 0;
    __syncthreads();

    unsigned int mypk[8]; int myrk[8];
#pragma unroll
    for (int k = 0; k < 8; k++) {
        int i = t + k * 1024;
        unsigned int pk = 0; int rk = 0;
        if (i < cnt) {
            pk = buf[(size_t)r * RC + i];
            rk = atomicAdd(&hist[pk >> 21], 1);
        }
        mypk[k] = pk; myrk[k] = rk;
    }
    __syncthreads();

    if (t < NRANGE) scanb[t] = hist[t];
    __syncthreads();
    for (int off = 1; off < NRANGE; off <<= 1) {
        int v = 0;
        if (t < NRANGE && t >= off) v = scanb[t - off];
        __syncthreads();
        if (t < NRANGE) scanb[t] += v;
        __syncthreads();
    }
    if (t < NRANGE) lofs[t + 1] = scanb[t];
    if (t == 0) lofs[0] = 0;
    __syncthreads();

#pragma unroll
    for (int k = 0; k < 8; k++) {
        int i = t + k * 1024;
        if (i < cnt) {
            unsigned int pk = mypk[k];
            sout[lofs[pk >> 21] + myrk[k]] = (int)(pk & 0x1FFFFFu);
        }
    }
    __syncthreads();

    for (int i = t; i < cnt; i += 1024) eid[(size_t)r * RC + i] = sout[i];
    if (t < nr) {
        node_off[sbeg + t] = r * RC + lofs[t];
        node_cnt[sbeg + t] = hist[t];
    }
}

// ---------------------------------------------------------------------------
// Segment-sum gather over the exact CSR.  SPLIT=4: thread (n,c,q) handles
// quarter c of node n's edge list, float4 quad q.  25K waves (R13 had 12.5K);
// per-thread dependent chains halve.  If this is null, random-row reads are
// transaction-bound and the pipeline is at its pattern-roofline.
// ---------------------------------------------------------------------------
__global__ __launch_bounds__(256) void k_gather(const float* __restrict__ ew,
                                                const int* __restrict__ node_off,
                                                const int* __restrict__ node_cnt,
                                                const int* __restrict__ eid,
                                                float* __restrict__ parts) {
    int i = blockIdx.x * 256 + threadIdx.x;     // over NN*SPLIT*8 = 1.6M (exact grid)
    int q = i & 7;
    int t2 = i >> 3;
    int c = t2 & 3;
    int n = t2 >> 2;
    const int qo = q << 2;

    const int beg = node_off[n];
    const int cnt = node_cnt[n];
    const int quarter = (cnt + 3) >> 2;
    int r0 = c * quarter;
    int r1 = r0 + quarter; if (r1 > cnt) r1 = cnt;
    const int* bucket = eid + beg;

    float4 acc = make_float4(0.f, 0.f, 0.f, 0.f);
    int r = r0;
    for (; r + 4 <= r1; r += 4) {
        int ea = bucket[r + 0];
        int eb = bucket[r + 1];
        int ec = bucket[r + 2];
        int ed = bucket[r + 3];
        float4 v0 = *reinterpret_cast<const float4*>(ew + (size_t)ea * D + qo);
        float4 v1 = *reinterpret_cast<const float4*>(ew + (size_t)eb * D + qo);
        float4 v2 = *reinterpret_cast<const float4*>(ew + (size_t)ec * D + qo);
        float4 v3 = *reinterpret_cast<const float4*>(ew + (size_t)ed * D + qo);
        acc.x += (v0.x + v1.x) + (v2.x + v3.x);
        acc.y += (v0.y + v1.y) + (v2.y + v3.y);
        acc.z += (v0.z + v1.z) + (v2.z + v3.z);
        acc.w += (v0.w + v1.w) + (v2.w + v3.w);
    }
    for (; r < r1; ++r) {
        int e0 = bucket[r];
        float4 v0 = *reinterpret_cast<const float4*>(ew + (size_t)e0 * D + qo);
        acc.x += v0.x; acc.y += v0.y; acc.z += v0.z; acc.w += v0.w;
    }
    *reinterpret_cast<float4*>(parts + ((size_t)c * NN + n) * D + qo) = acc;
}

// ---------------------------------------------------------------------------
// node_term (bf16) = x@w_x + (p0+p1+p2+p3)@w_ew_j
// ---------------------------------------------------------------------------
__global__ __launch_bounds__(256) void k_node(const float* __restrict__ x,
                                              const float* __restrict__ parts,
                                              const float* __restrict__ w_x,
                                              const float* __restrict__ w_ew_j,
                                              unsigned short* __restrict__ node_term) {
    int i = blockIdx.x * 256 + threadIdx.x;     // n*32 + o (exact grid)
    int n = i >> 5, o = i & 31;
    const float* p0 = parts + ((size_t)0 * NN + n) * D;
    const float* p1 = parts + ((size_t)1 * NN + n) * D;
    const float* p2 = parts + ((size_t)2 * NN + n) * D;
    const float* p3 = parts + ((size_t)3 * NN + n) * D;
    float acc = 0.f;
#pragma unroll
    for (int k = 0; k < D; k++) {
        float sw = (p0[k] + p1[k]) + (p2[k] + p3[k]);
        acc += x[(size_t)n * D + k] * w_x[k * D + o] + sw * w_ew_j[k * D + o];
    }
    node_term[i] = f2b(acc);
}

// ---------------------------------------------------------------------------
// out[e][4q..] = nt[s][q] + nt[d][q] + sum_k ew[e][k]*w_ew_i[k][4q..]
// R13 exact (best k_edge measured: 127us, VGPR 32, occ 71%).
// ---------------------------------------------------------------------------
__global__ __launch_bounds__(256) void k_edge(const float* __restrict__ ew,
                                              const int* __restrict__ src,
                                              const int* __restrict__ dst,
                                              const unsigned short* __restrict__ nt,
                                              const float* __restrict__ w_ew_i,
                                              float* __restrict__ out) {
    __shared__ float wsm[D * D];
    {
        int t4 = threadIdx.x * 4;
        *reinterpret_cast<float4*>(wsm + t4) =
            *reinterpret_cast<const float4*>(w_ew_i + t4);
    }
    __syncthreads();

    int i = blockIdx.x * 256 + threadIdx.x;     // over NE*8 = 12.8M (exact grid)
    int e = i >> 3, q = i & 7;
    int s = src[e];
    int d = dst[e];
    const int qo = q << 2;

    ushort4 a4 = *reinterpret_cast<const ushort4*>(nt + (size_t)s * D + qo);
    ushort4 b4 = *reinterpret_cast<const ushort4*>(nt + (size_t)d * D + qo);
    float4 acc = make_float4(b2f(a4.x) + b2f(b4.x),
                             b2f(a4.y) + b2f(b4.y),
                             b2f(a4.z) + b2f(b4.z),
                             b2f(a4.w) + b2f(b4.w));

    const float4* ewp = reinterpret_cast<const float4*>(ew + (size_t)e * D);
#pragma unroll
    for (int kq = 0; kq < 8; kq++) {
        float4 e4 = ewp[kq];
        const float ev[4] = {e4.x, e4.y, e4.z, e4.w};
#pragma unroll
        for (int j = 0; j < 4; j++) {
            const int k = kq * 4 + j;
            float4 wv = *reinterpret_cast<const float4*>(wsm + k * D + qo);
            acc.x += ev[j] * wv.x;
            acc.y += ev[j] * wv.y;
            acc.z += ev[j] * wv.z;
            acc.w += ev[j] * wv.w;
        }
    }

    *reinterpret_cast<float4*>(out + (size_t)e * D + qo) = acc;
}

// ---------------------------------------------------------------------------
extern "C" void kernel_launch(void* const* d_in, const int* in_sizes, int n_in,
                              void* d_out, int out_size, void* d_ws, size_t ws_size,
                              hipStream_t stream) {
    const float* x      = (const float*)d_in[0];
    const int*   ei     = (const int*)d_in[1];
    const float* ew     = (const float*)d_in[2];
    const float* w_x    = (const float*)d_in[3];
    const float* w_ew_i = (const float*)d_in[4];
    const float* w_ew_j = (const float*)d_in[5];
    float*       out    = (float*)d_out;

    const int* src = ei;            // edge_index[0]
    const int* dst = ei + NE;       // edge_index[1]

    // workspace (~42 MB).  nt (bf16, 3.2MB) overlays buf (dead after part2).
    float*        parts    = (float*)d_ws;                       // [4][NN][D] 25.6 MB
    int*          node_off = (int*)(parts + (size_t)SPLIT * NN * D); // [NN]   200 KB
    int*          node_cnt = node_off + NN;                      // [NN]       200 KB
    int*          cursor   = node_cnt + NN;                      // [NRANGE]     1 KB
    unsigned int* buf      = (unsigned int*)(cursor + NRANGE);   // [NRANGE][RC] 8 MB
    int*          eid      = (int*)(buf + (size_t)NRANGE * RC);  // [NRANGE][RC] 8 MB
    unsigned short* ntb    = (unsigned short*)buf;               // [NN][D] bf16 overlay

    hipMemsetAsync(cursor, 0, NRANGE * sizeof(int), stream);

    k_part1 <<<(NE + EPB - 1) / EPB,  1024, 0, stream>>>(src, cursor, buf);
    k_part2 <<<NRANGE,                1024, 0, stream>>>(cursor, buf, eid, node_off, node_cnt);
    k_gather<<<NN * SPLIT * 8 / 256,  256,  0, stream>>>(ew, node_off, node_cnt, eid, parts);
    k_node  <<<NN * D / 256,          256,  0, stream>>>(x, parts, w_x, w_ew_j, ntb);
    k_edge  <<<NE * 8 / 256,          256,  0, stream>>>(ew, src, dst, ntb, w_ew_i, out);
}

// Round 17
// 237.841 us; speedup vs baseline: 1.1610x; 1.0634x over previous
//
#include <hip/hip_runtime.h>

#define NN 50000
#define NE 1600000
#define D  32
#define NRANGE 256
#define RC  8192      // entries per range region; E[6250], +24 sigma
#define EPB 16384     // edges per pass-1 block
#define SPLIT 2       // gather concurrency split (R16 probe: 4 regressed; 2 is optimal)

__device__ __forceinline__ float b2f(unsigned short v) {
    return __uint_as_float(((unsigned)v) << 16);
}
__device__ __forceinline__ unsigned short f2b(float f) {   // round-to-nearest-even
    unsigned u = __float_as_uint(f);
    u += 0x7FFFu + ((u >> 16) & 1u);
    return (unsigned short)(u >> 16);
}

__device__ __forceinline__ int range_of(int s)  { return (int)(((unsigned)s * 256u) / 50000u); }
__device__ __forceinline__ int range_beg(int r) { return (int)(((unsigned)r * 50000u + 255u) >> 8); }

// ---------------------------------------------------------------------------
// Pass 1: partition edges into 256 node-range regions, COALESCED writes.
// ---------------------------------------------------------------------------
__global__ __launch_bounds__(1024) void k_part1(const int* __restrict__ src,
                                                int* __restrict__ cursor,
                                                unsigned int* __restrict__ buf) {
    __shared__ unsigned int sbuf[EPB];       // 64 KB
    __shared__ int hist[NRANGE];
    __shared__ int scanb[NRANGE];
    __shared__ int lofs[NRANGE + 1];
    __shared__ int gbase[NRANGE];

    const int t = threadIdx.x;
    const long long e0 = (long long)blockIdx.x * EPB;

    for (int r = t; r < NRANGE; r += 1024) hist[r] = 0;
    __syncthreads();

    int myr[16], myrank[16], mys[16];
#pragma unroll
    for (int k = 0; k < 16; k++) {
        long long e = e0 + t + (long long)k * 1024;
        int r = -1, rk = 0, s = 0;
        if (e < NE) {
            s = src[e];
            r = range_of(s);
            rk = atomicAdd(&hist[r], 1);
        }
        myr[k] = r; myrank[k] = rk; mys[k] = s;
    }
    __syncthreads();

    if (t < NRANGE) {
        gbase[t] = atomicAdd(&cursor[t], hist[t]);
        scanb[t] = hist[t];
    }
    __syncthreads();
    for (int off = 1; off < NRANGE; off <<= 1) {       // Hillis-Steele inclusive
        int v = 0;
        if (t < NRANGE && t >= off) v = scanb[t - off];
        __syncthreads();
        if (t < NRANGE) scanb[t] += v;
        __syncthreads();
    }
    if (t < NRANGE) lofs[t + 1] = scanb[t];
    if (t == 0) lofs[0] = 0;
    __syncthreads();

#pragma unroll
    for (int k = 0; k < 16; k++) {
        if (myr[k] >= 0) {
            int r = myr[k];
            unsigned int pk = (unsigned int)(e0 + t + (long long)k * 1024)
                            | ((unsigned int)(mys[k] - range_beg(r)) << 21);
            sbuf[lofs[r] + myrank[k]] = pk;
        }
    }
    __syncthreads();

    const int total = lofs[NRANGE];
    for (int i = t; i < total; i += 1024) {
        int lo = 0, hi = NRANGE - 1;                   // find r: lofs[r]<=i<lofs[r+1]
        while (lo < hi) { int mid = (lo + hi + 1) >> 1; if (lofs[mid] <= i) lo = mid; else hi = mid - 1; }
        buf[(size_t)lo * RC + gbase[lo] + (i - lofs[lo])] = sbuf[i];
    }
}

// ---------------------------------------------------------------------------
// Pass 2: one block per range; LDS-sort entries by local node id -> exact CSR.
// ---------------------------------------------------------------------------
__global__ __launch_bounds__(1024) void k_part2(const int* __restrict__ cursor,
                                                const unsigned int* __restrict__ buf,
                                                int* __restrict__ eid,
                                                int* __restrict__ node_off,
                                                int* __restrict__ node_cnt) {
    __shared__ int sout[RC];                 // 32 KB
    __shared__ int hist[NRANGE];
    __shared__ int scanb[NRANGE];
    __shared__ int lofs[NRANGE + 1];

    const int r = blockIdx.x;
    const int t = threadIdx.x;
    int cnt = cursor[r];
    if (cnt > RC) cnt = RC;                  // impossible; guards OOB
    const int sbeg = range_beg(r);
    const int nr = range_beg(r + 1) - sbeg;  // nodes in this range (<=196)

    for (int i = t; i < NRANGE; i += 1024) hist[i] = 0;
    __syncthreads();

    unsigned int mypk[8]; int myrk[8];
#pragma unroll
    for (int k = 0; k < 8; k++) {
        int i = t + k * 1024;
        unsigned int pk = 0; int rk = 0;
        if (i < cnt) {
            pk = buf[(size_t)r * RC + i];
            rk = atomicAdd(&hist[pk >> 21], 1);
        }
        mypk[k] = pk; myrk[k] = rk;
    }
    __syncthreads();

    if (t < NRANGE) scanb[t] = hist[t];
    __syncthreads();
    for (int off = 1; off < NRANGE; off <<= 1) {
        int v = 0;
        if (t < NRANGE && t >= off) v = scanb[t - off];
        __syncthreads();
        if (t < NRANGE) scanb[t] += v;
        __syncthreads();
    }
    if (t < NRANGE) lofs[t + 1] = scanb[t];
    if (t == 0) lofs[0] = 0;
    __syncthreads();

#pragma unroll
    for (int k = 0; k < 8; k++) {
        int i = t + k * 1024;
        if (i < cnt) {
            unsigned int pk = mypk[k];
            sout[lofs[pk >> 21] + myrk[k]] = (int)(pk & 0x1FFFFFu);
        }
    }
    __syncthreads();

    for (int i = t; i < cnt; i += 1024) eid[(size_t)r * RC + i] = sout[i];
    if (t < nr) {
        node_off[sbeg + t] = r * RC + lofs[t];
        node_cnt[sbeg + t] = hist[t];
    }
}

// ---------------------------------------------------------------------------
// Segment-sum gather over the exact CSR (R13 exact; SPLIT=2 is the measured
// optimum -- R16's SPLIT=4 probe showed transaction-bound behavior).
// ---------------------------------------------------------------------------
__global__ __launch_bounds__(256) void k_gather(const float* __restrict__ ew,
                                                const int* __restrict__ node_off,
                                                const int* __restrict__ node_cnt,
                                                const int* __restrict__ eid,
                                                float* __restrict__ parts) {
    int i = blockIdx.x * 256 + threadIdx.x;     // over NN*SPLIT*8 = 800K (exact grid)
    int q = i & 7;
    int t2 = i >> 3;
    int c = t2 & 1;
    int n = t2 >> 1;
    const int qo = q << 2;

    const int beg = node_off[n];
    const int cnt = node_cnt[n];
    const int half = (cnt + 1) >> 1;
    int r0 = c * half;
    int r1 = r0 + half; if (r1 > cnt) r1 = cnt;
    const int* bucket = eid + beg;

    float4 acc = make_float4(0.f, 0.f, 0.f, 0.f);
    int r = r0;
    for (; r + 4 <= r1; r += 4) {
        int ea = bucket[r + 0];
        int eb = bucket[r + 1];
        int ec = bucket[r + 2];
        int ed = bucket[r + 3];
        float4 v0 = *reinterpret_cast<const float4*>(ew + (size_t)ea * D + qo);
        float4 v1 = *reinterpret_cast<const float4*>(ew + (size_t)eb * D + qo);
        float4 v2 = *reinterpret_cast<const float4*>(ew + (size_t)ec * D + qo);
        float4 v3 = *reinterpret_cast<const float4*>(ew + (size_t)ed * D + qo);
        acc.x += (v0.x + v1.x) + (v2.x + v3.x);
        acc.y += (v0.y + v1.y) + (v2.y + v3.y);
        acc.z += (v0.z + v1.z) + (v2.z + v3.z);
        acc.w += (v0.w + v1.w) + (v2.w + v3.w);
    }
    for (; r < r1; ++r) {
        int e0 = bucket[r];
        float4 v0 = *reinterpret_cast<const float4*>(ew + (size_t)e0 * D + qo);
        acc.x += v0.x; acc.y += v0.y; acc.z += v0.z; acc.w += v0.w;
    }
    *reinterpret_cast<float4*>(parts + ((size_t)c * NN + n) * D + qo) = acc;
}

// ---------------------------------------------------------------------------
// node_term (bf16) = x@w_x + (p0+p1)@w_ew_j
// ---------------------------------------------------------------------------
__global__ __launch_bounds__(256) void k_node(const float* __restrict__ x,
                                              const float* __restrict__ parts,
                                              const float* __restrict__ w_x,
                                              const float* __restrict__ w_ew_j,
                                              unsigned short* __restrict__ node_term) {
    int i = blockIdx.x * 256 + threadIdx.x;     // n*32 + o (exact grid)
    int n = i >> 5, o = i & 31;
    const float* p0 = parts + (size_t)n * D;
    const float* p1 = parts + ((size_t)NN + n) * D;
    float acc = 0.f;
#pragma unroll
    for (int k = 0; k < D; k++) {
        float sw = p0[k] + p1[k];
        acc += x[(size_t)n * D + k] * w_x[k * D + o] + sw * w_ew_j[k * D + o];
    }
    node_term[i] = f2b(acc);
}

// ---------------------------------------------------------------------------
// out[e][4q..] = nt[s][q] + nt[d][q] + sum_k ew[e][k]*w_ew_i[k][4q..]
// R13 exact (best measured: 127us, VGPR 32, occ 71%; three structural
// variants all converge at this pattern ceiling).
// ---------------------------------------------------------------------------
__global__ __launch_bounds__(256) void k_edge(const float* __restrict__ ew,
                                              const int* __restrict__ src,
                                              const int* __restrict__ dst,
                                              const unsigned short* __restrict__ nt,
                                              const float* __restrict__ w_ew_i,
                                              float* __restrict__ out) {
    __shared__ float wsm[D * D];
    {
        int t4 = threadIdx.x * 4;
        *reinterpret_cast<float4*>(wsm + t4) =
            *reinterpret_cast<const float4*>(w_ew_i + t4);
    }
    __syncthreads();

    int i = blockIdx.x * 256 + threadIdx.x;     // over NE*8 = 12.8M (exact grid)
    int e = i >> 3, q = i & 7;
    int s = src[e];
    int d = dst[e];
    const int qo = q << 2;

    ushort4 a4 = *reinterpret_cast<const ushort4*>(nt + (size_t)s * D + qo);
    ushort4 b4 = *reinterpret_cast<const ushort4*>(nt + (size_t)d * D + qo);
    float4 acc = make_float4(b2f(a4.x) + b2f(b4.x),
                             b2f(a4.y) + b2f(b4.y),
                             b2f(a4.z) + b2f(b4.z),
                             b2f(a4.w) + b2f(b4.w));

    const float4* ewp = reinterpret_cast<const float4*>(ew + (size_t)e * D);
#pragma unroll
    for (int kq = 0; kq < 8; kq++) {
        float4 e4 = ewp[kq];
        const float ev[4] = {e4.x, e4.y, e4.z, e4.w};
#pragma unroll
        for (int j = 0; j < 4; j++) {
            const int k = kq * 4 + j;
            float4 wv = *reinterpret_cast<const float4*>(wsm + k * D + qo);
            acc.x += ev[j] * wv.x;
            acc.y += ev[j] * wv.y;
            acc.z += ev[j] * wv.z;
            acc.w += ev[j] * wv.w;
        }
    }

    *reinterpret_cast<float4*>(out + (size_t)e * D + qo) = acc;
}

// ---------------------------------------------------------------------------
extern "C" void kernel_launch(void* const* d_in, const int* in_sizes, int n_in,
                              void* d_out, int out_size, void* d_ws, size_t ws_size,
                              hipStream_t stream) {
    const float* x      = (const float*)d_in[0];
    const int*   ei     = (const int*)d_in[1];
    const float* ew     = (const float*)d_in[2];
    const float* w_x    = (const float*)d_in[3];
    const float* w_ew_i = (const float*)d_in[4];
    const float* w_ew_j = (const float*)d_in[5];
    float*       out    = (float*)d_out;

    const int* src = ei;            // edge_index[0]
    const int* dst = ei + NE;       // edge_index[1]

    // workspace (~29.3 MB).  nt (bf16, 3.2MB) overlays buf (dead after part2).
    float*        parts    = (float*)d_ws;                       // [2][NN][D] 12.8 MB
    int*          node_off = (int*)(parts + (size_t)SPLIT * NN * D); // [NN]   200 KB
    int*          node_cnt = node_off + NN;                      // [NN]       200 KB
    int*          cursor   = node_cnt + NN;                      // [NRANGE]     1 KB
    unsigned int* buf      = (unsigned int*)(cursor + NRANGE);   // [NRANGE][RC] 8 MB
    int*          eid      = (int*)(buf + (size_t)NRANGE * RC);  // [NRANGE][RC] 8 MB
    unsigned short* ntb    = (unsigned short*)buf;               // [NN][D] bf16 overlay

    hipMemsetAsync(cursor, 0, NRANGE * sizeof(int), stream);

    k_part1 <<<(NE + EPB - 1) / EPB,  1024, 0, stream>>>(src, cursor, buf);
    k_part2 <<<NRANGE,                1024, 0, stream>>>(cursor, buf, eid, node_off, node_cnt);
    k_gather<<<NN * SPLIT * 8 / 256,  256,  0, stream>>>(ew, node_off, node_cnt, eid, parts);
    k_node  <<<NN * D / 256,          256,  0, stream>>>(x, parts, w_x, w_ew_j, ntb);
    k_edge  <<<NE * 8 / 256,          256,  0, stream>>>(ew, src, dst, ntb, w_ew_i, out);
}